// Round 16
// baseline (158.436 us; speedup 1.0000x reference)
//
#include <hip/hip_runtime.h>
#include <cstdint>
#include <cstddef>

#define DF 64          // feature dim
#define NREL 8         // relations
#define DPB 64         // dst nodes per coarse bucket
#define DPB_SHIFT 6
#define NBMAX 1024     // max coarse buckets supported by LDS kernels
#define EPB 4096       // edges per binning block. DO NOT SHRINK: per-block
                       // cursor setup is O(NB); EPB=2048 regressed twice (R8,R13)
#define BCAP 3072      // per-bucket record capacity in gather LDS
#define NKEY 512       // (local_dst 6b << 3) | rel 3b
#define SBST 72        // sbuf row stride (bf16): 64 + 8 pad

typedef __attribute__((ext_vector_type(8))) short bf16x8;
typedef __attribute__((ext_vector_type(4))) float f32x4;

// ---- bf16 helpers (RNE) ---------------------------------------------------
static __device__ __forceinline__ unsigned short f2bf(float f) {
  unsigned int u = __float_as_uint(f);
  u += 0x7FFFu + ((u >> 16) & 1u);
  return (unsigned short)(u >> 16);
}
static __device__ __forceinline__ float bf2f(unsigned short s) {
  return __uint_as_float((unsigned int)s << 16);
}

// ---------------------------------------------------------------------------
// prep: blocks 0..17 pack weights into bf16 MFMA A-fragments
//       (A[row=f][k] = W[k][f]; mats 0..7=W1, 8=root1, 9..16=W2, 17=root2);
//       blocks 18.. convert feat fp32 -> xb bf16; block 18 zeroes bcnt.
// ---------------------------------------------------------------------------
__global__ __launch_bounds__(512) void prep(
    const float* __restrict__ W1, const float* __restrict__ rt1,
    const float* __restrict__ W2, const float* __restrict__ rt2,
    bf16x8* __restrict__ frag,
    const float* __restrict__ x, unsigned short* __restrict__ xb, int n8,
    int* __restrict__ bcnt, int NB)
{
  const int b = blockIdx.x;
  const int t = threadIdx.x;

  if (b < 18) {
    const float* W = (b < 8)  ? (W1 + (size_t)b * 4096)
                   : (b == 8) ? rt1
                   : (b < 17) ? (W2 + (size_t)(b - 9) * 4096)
                              : rt2;
    const int ft = t >> 7;
    const int ks = (t >> 6) & 1;
    const int l  = t & 63;
    const int col = ft * 16 + (l & 15);
    const int k0  = ks * 32 + (l >> 4) * 8;
    bf16x8 f;
#pragma unroll
    for (int j = 0; j < 8; ++j)
      f[j] = (short)f2bf(W[(size_t)(k0 + j) * 64 + col]);
    frag[(((size_t)b * 4 + ft) * 2 + ks) * 64 + l] = f;
    return;
  }

  if (b == 18) {
    for (int i = t; i < NB; i += 512) bcnt[i] = 0;
  }

  const int i = (b - 18) * 512 + t;
  if (i < n8) {
    const float4 v0 = *(const float4*)&x[(size_t)i * 8];
    const float4 v1 = *(const float4*)&x[(size_t)i * 8 + 4];
    uint4 pk;
    pk.x = (unsigned)f2bf(v0.x) | ((unsigned)f2bf(v0.y) << 16);
    pk.y = (unsigned)f2bf(v0.z) | ((unsigned)f2bf(v0.w) << 16);
    pk.z = (unsigned)f2bf(v1.x) | ((unsigned)f2bf(v1.y) << 16);
    pk.w = (unsigned)f2bf(v1.z) | ((unsigned)f2bf(v1.w) << 16);
    *(uint4*)&xb[(size_t)i * 8] = pk;
  }
}

// ---------------------------------------------------------------------------
// CSR-lite build (one-pass scatter via saved per-block reservations)
// record (u32): rel[3] << 24 | src[17] << 7 | local_dst[6]
// ---------------------------------------------------------------------------
__global__ __launch_bounds__(512) void bucket_count(
    const int* __restrict__ dst, int* __restrict__ bcnt,
    int* __restrict__ relof, int E, int NB)
{
  __shared__ int lh[NBMAX];
  const int t = threadIdx.x;
  for (int i = t; i < NB; i += 512) lh[i] = 0;
  __syncthreads();
  const int base = blockIdx.x * EPB;
  const int cnt = min(EPB, E - base);
  for (int k = t; k < cnt; k += 512)
    atomicAdd(&lh[dst[base + k] >> DPB_SHIFT], 1);
  __syncthreads();
  int* rrow = relof + (size_t)blockIdx.x * NB;
  for (int i = t; i < NB; i += 512) {
    int c = lh[i];
    rrow[i] = c ? atomicAdd(&bcnt[i], c) : 0;
  }
}

__global__ __launch_bounds__(1024) void scan_buckets(
    const int* __restrict__ bcnt, int* __restrict__ boff, int NB, int E)
{
  __shared__ int sc[1024];
  const int t = threadIdx.x;
  int v = (t < NB) ? bcnt[t] : 0;
  sc[t] = v;
  __syncthreads();
  for (int off = 1; off < 1024; off <<= 1) {
    int u = (t >= off) ? sc[t - off] : 0;
    __syncthreads();
    sc[t] += u;
    __syncthreads();
  }
  if (t < NB) boff[t] = sc[t] - v;
  if (t == 0) boff[NB] = E;
}

__global__ __launch_bounds__(512) void bin_scatter(
    const int* __restrict__ src, const int* __restrict__ dst,
    const int* __restrict__ et,
    const int* __restrict__ boff, const int* __restrict__ relof,
    unsigned int* __restrict__ binned, int E, int NB)
{
  __shared__ int cur[NBMAX];
  const int t = threadIdx.x;
  const int* rrow = relof + (size_t)blockIdx.x * NB;
  for (int i = t; i < NB; i += 512) cur[i] = boff[i] + rrow[i];
  __syncthreads();
  const int base = blockIdx.x * EPB;
  const int cnt = min(EPB, E - base);
  for (int k = t; k < cnt; k += 512) {
    int e = base + k;
    int d = dst[e];
    int pos = atomicAdd(&cur[d >> DPB_SHIFT], 1);
    binned[pos] = ((unsigned)et[e] << 24) | ((unsigned)src[e] << 7) |
                  ((unsigned)d & (DPB - 1));
  }
}

// ---------------------------------------------------------------------------
// gather_gemm: per 64-dst bucket, fused aggregation + GEMM, per-rel
// interleaved so only 8 accumulator floats are live across barriers
// (R15's acc[8][8] spilled to scratch: VGPR=56, FETCH=52 MB).
//   for r in 0..7: gather rel r sums into acc8 -> stage to padded LDS ->
//                  barrier -> 8 waves MFMA their (node-group x f-tile) ->
//                  barrier
//   then root slab from xb rows + bias/relu epilogue (+xb_next emit).
// ---------------------------------------------------------------------------
static __device__ __forceinline__ void gadd(
    float* __restrict__ acc, const uint4& u)
{
  acc[0] += bf2f((unsigned short)u.x);
  acc[1] += bf2f((unsigned short)(u.x >> 16));
  acc[2] += bf2f((unsigned short)u.y);
  acc[3] += bf2f((unsigned short)(u.y >> 16));
  acc[4] += bf2f((unsigned short)u.z);
  acc[5] += bf2f((unsigned short)(u.z >> 16));
  acc[6] += bf2f((unsigned short)u.w);
  acc[7] += bf2f((unsigned short)(u.w >> 16));
}

__global__ __launch_bounds__(512, 4) void gather_gemm(
    const unsigned int* __restrict__ binned,
    const int* __restrict__ boff,
    const unsigned short* __restrict__ xb,   // [N][64] bf16 (L2-resident)
    const bf16x8* __restrict__ wfrag,        // [9][4][2][64] layer base
    const float* __restrict__ bias,          // [64]
    float* __restrict__ out,                 // [N][64] fp32
    unsigned short* __restrict__ xbn,        // [N][64] bf16 or null
    int N, int do_relu)
{
  __shared__ unsigned int srt[BCAP];              // 12 KB
  __shared__ int h[NKEY], sc[NKEY], cur[NKEY];    // 6 KB
  __shared__ int wsum[8];
  __shared__ unsigned short sbuf[64 * SBST];      // 9.2 KB, padded stride

  const int t = threadIdx.x;
  const int b = blockIdx.x;
  const int beg = boff[b], end = boff[b + 1];
  const int m = min(end - beg, BCAP);

  // ---- phase 1: key sort ----
  h[t] = 0;
  __syncthreads();
  for (int k = t; k < m; k += 512) {
    unsigned w = binned[beg + k];
    atomicAdd(&h[((w & (DPB - 1)) << 3) | (w >> 24)], 1);
  }
  __syncthreads();
  {
    const int lane = t & 63;
    const int wvv = t >> 6;
    int v = h[t];
    int incl = v;
#pragma unroll
    for (int off = 1; off < 64; off <<= 1) {
      int u = __shfl_up(incl, off);
      if (lane >= off) incl += u;
    }
    if (lane == 63) wsum[wvv] = incl;
    __syncthreads();
    int wo = 0;
    for (int w2 = 0; w2 < wvv; ++w2) wo += wsum[w2];
    sc[t] = incl + wo;
    cur[t] = sc[t] - v;
  }
  __syncthreads();
  for (int k = t; k < m; k += 512) {
    unsigned w = binned[beg + k];
    int pos = atomicAdd(&cur[((w & (DPB - 1)) << 3) | (w >> 24)], 1);
    srt[pos] = w;
  }
  __syncthreads();

  // ---- phase 2: per-rel interleaved gather + MFMA ----
  const int nl  = t >> 3;            // 0..63 local node (gather role)
  const int l8  = (t & 7) * 8;       // feature offset (8 bf16 = 16B)
  const int ovf = end - beg - BCAP;

  const int l   = t & 63;
  const int wv  = t >> 6;            // wave 0..7 (MFMA role)
  const int lr  = l & 15;
  const int lg  = l >> 4;
  const int ng  = wv & 3;            // 16-node group within bucket
  const int mtb = (wv >> 2) * 2;     // this wave's first f-tile (of 2)

  f32x4 accm[2];
  accm[0] = (f32x4)(0.f);
  accm[1] = (f32x4)(0.f);

#define XADDR(wv_) ((const uint4*)&xb[(((size_t)(((wv_) >> 7) & 0x1FFFFu)) << 6) + l8])
  for (int r = 0; r < NREL; ++r) {
    float acc8[8];
#pragma unroll
    for (int i = 0; i < 8; ++i) acc8[i] = 0.f;

    {
      const int kk = (nl << 3) | r;
      int p = sc[kk] - h[kk];
      const int pe = sc[kk];
      for (; p + 3 < pe; p += 4) {
        unsigned w0 = srt[p],     w1 = srt[p + 1];
        unsigned w2 = srt[p + 2], w3 = srt[p + 3];
        uint4 u0 = *XADDR(w0), u1 = *XADDR(w1);
        uint4 u2 = *XADDR(w2), u3 = *XADDR(w3);
        gadd(acc8, u0); gadd(acc8, u1); gadd(acc8, u2); gadd(acc8, u3);
      }
      for (; p < pe; ++p) {
        unsigned w0 = srt[p];
        uint4 u0 = *XADDR(w0);
        gadd(acc8, u0);
      }
      if (ovf > 0) {   // slow path, ~never taken
        for (int k = 0; k < ovf; ++k) {
          unsigned w0 = binned[beg + BCAP + k];
          if ((int)(w0 & (DPB - 1)) == nl && (int)(w0 >> 24) == r) {
            uint4 u0 = *XADDR(w0);
            gadd(acc8, u0);
          }
        }
      }
    }

    uint4 pk;
    pk.x = (unsigned)f2bf(acc8[0]) | ((unsigned)f2bf(acc8[1]) << 16);
    pk.y = (unsigned)f2bf(acc8[2]) | ((unsigned)f2bf(acc8[3]) << 16);
    pk.z = (unsigned)f2bf(acc8[4]) | ((unsigned)f2bf(acc8[5]) << 16);
    pk.w = (unsigned)f2bf(acc8[6]) | ((unsigned)f2bf(acc8[7]) << 16);
    *(uint4*)&sbuf[nl * SBST + l8] = pk;
    __syncthreads();

    bf16x8 bfr[2];
#pragma unroll
    for (int ks = 0; ks < 2; ++ks)
      bfr[ks] = *(const bf16x8*)&sbuf[(ng * 16 + lr) * SBST + ks * 32 + lg * 8];

    const bf16x8* wf = wfrag + (size_t)r * 512;
#pragma unroll
    for (int i = 0; i < 2; ++i)
#pragma unroll
      for (int ks = 0; ks < 2; ++ks) {
        bf16x8 a = wf[((mtb + i) * 2 + ks) * 64 + l];
        accm[i] = __builtin_amdgcn_mfma_f32_16x16x32_bf16(a, bfr[ks], accm[i],
                                                          0, 0, 0);
      }
    __syncthreads();
  }
#undef XADDR

  // ---- phase 3: root slab (B = xb rows of this block's contiguous nodes) ----
  const int node = (b << DPB_SHIFT) + ng * 16 + lr;
  {
    bf16x8 bfr[2];
#pragma unroll
    for (int ks = 0; ks < 2; ++ks) {
      if (node < N)
        bfr[ks] = *(const bf16x8*)&xb[((size_t)node << 6) + ks * 32 + lg * 8];
      else
        bfr[ks] = (bf16x8)(short)0;
    }
    const bf16x8* wf = wfrag + (size_t)8 * 512;
#pragma unroll
    for (int i = 0; i < 2; ++i)
#pragma unroll
      for (int ks = 0; ks < 2; ++ks) {
        bf16x8 a = wf[((mtb + i) * 2 + ks) * 64 + l];
        accm[i] = __builtin_amdgcn_mfma_f32_16x16x32_bf16(a, bfr[ks], accm[i],
                                                          0, 0, 0);
      }
  }

  // ---- phase 4: epilogue ----
  if (node < N) {
#pragma unroll
    for (int i = 0; i < 2; ++i) {
      const int f0 = (mtb + i) * 16 + lg * 4;
      float4 bb = *(const float4*)&bias[f0];
      float4 v = make_float4(accm[i][0] + bb.x, accm[i][1] + bb.y,
                             accm[i][2] + bb.z, accm[i][3] + bb.w);
      if (do_relu) {
        v.x = fmaxf(v.x, 0.f); v.y = fmaxf(v.y, 0.f);
        v.z = fmaxf(v.z, 0.f); v.w = fmaxf(v.w, 0.f);
      }
      *(float4*)&out[((size_t)node << 6) + f0] = v;
      if (xbn) {
        uint2 pk;
        pk.x = (unsigned)f2bf(v.x) | ((unsigned)f2bf(v.y) << 16);
        pk.y = (unsigned)f2bf(v.z) | ((unsigned)f2bf(v.w) << 16);
        *(uint2*)&xbn[((size_t)node << 6) + f0] = pk;
      }
    }
  }
}

// ---------------------------------------------------------------------------
// FALLBACK path kernels (ws too small): fp32 vector transform + atomic scatter
// ---------------------------------------------------------------------------
__global__ __launch_bounds__(128) void rgcn_transform(
    const float* __restrict__ x,
    const float* __restrict__ Wc,
    unsigned short* __restrict__ hb,
    int N)
{
  const int r = blockIdx.y;
  const float* W = Wc + (size_t)r * DF * DF;

  __shared__ float Ws[DF * DF];
  __shared__ float Xs[128 * 65];

  const int tid = threadIdx.x;
  const int n0 = blockIdx.x * 128;
  const int nrem = N - n0;

  {
    const float4* Wv = (const float4*)W;
    float4* Wsv = (float4*)Ws;
#pragma unroll
    for (int j = 0; j < 8; ++j) Wsv[tid + j * 128] = Wv[tid + j * 128];
  }
#pragma unroll
  for (int j = 0; j < 16; ++j) {
    int idx = tid + j * 128;
    int n = idx >> 4;
    int c4 = (idx & 15) * 4;
    float4 v = make_float4(0.f, 0.f, 0.f, 0.f);
    if (n < nrem) v = *(const float4*)&x[(size_t)(n0 + n) * DF + c4];
    float* p = &Xs[n * 65 + c4];
    p[0] = v.x; p[1] = v.y; p[2] = v.z; p[3] = v.w;
  }
  __syncthreads();

  const int fg = (tid & 7) * 8;
  const int ng = (tid >> 3) * 8;

  float4 a0[8], a1[8];
#pragma unroll
  for (int i = 0; i < 8; ++i) {
    a0[i] = make_float4(0.f, 0.f, 0.f, 0.f);
    a1[i] = make_float4(0.f, 0.f, 0.f, 0.f);
  }

#pragma unroll 4
  for (int d = 0; d < DF; ++d) {
    float4 w0 = *(const float4*)&Ws[d * DF + fg];
    float4 w1 = *(const float4*)&Ws[d * DF + fg + 4];
#pragma unroll
    for (int i = 0; i < 8; ++i) {
      float xv = Xs[(ng + i) * 65 + d];
      a0[i].x += xv * w0.x; a0[i].y += xv * w0.y;
      a0[i].z += xv * w0.z; a0[i].w += xv * w0.w;
      a1[i].x += xv * w1.x; a1[i].y += xv * w1.y;
      a1[i].z += xv * w1.z; a1[i].w += xv * w1.w;
    }
  }

#pragma unroll
  for (int i = 0; i < 8; ++i) {
    int n = ng + i;
    if (n < nrem) {
      uint4 pk;
      pk.x = (unsigned)f2bf(a0[i].x) | ((unsigned)f2bf(a0[i].y) << 16);
      pk.y = (unsigned)f2bf(a0[i].z) | ((unsigned)f2bf(a0[i].w) << 16);
      pk.z = (unsigned)f2bf(a1[i].x) | ((unsigned)f2bf(a1[i].y) << 16);
      pk.w = (unsigned)f2bf(a1[i].z) | ((unsigned)f2bf(a1[i].w) << 16);
      unsigned short* op = hb + (((size_t)r * N + (n0 + n)) << 6) + fg;
      *(uint4*)op = pk;
    }
  }
}

__global__ __launch_bounds__(128) void rgcn_root_epilogue(
    const float* __restrict__ x,
    const float* __restrict__ root,
    const float* __restrict__ bias,
    float* __restrict__ out,
    int N, int mode)
{
  __shared__ float Ws[DF * DF];
  __shared__ float Xs[128 * 65];

  const int tid = threadIdx.x;
  const int n0 = blockIdx.x * 128;
  const int nrem = N - n0;

  {
    const float4* Wv = (const float4*)root;
    float4* Wsv = (float4*)Ws;
#pragma unroll
    for (int j = 0; j < 8; ++j) Wsv[tid + j * 128] = Wv[tid + j * 128];
  }
#pragma unroll
  for (int j = 0; j < 16; ++j) {
    int idx = tid + j * 128;
    int n = idx >> 4;
    int c4 = (idx & 15) * 4;
    float4 v = make_float4(0.f, 0.f, 0.f, 0.f);
    if (n < nrem) v = *(const float4*)&x[(size_t)(n0 + n) * DF + c4];
    float* p = &Xs[n * 65 + c4];
    p[0] = v.x; p[1] = v.y; p[2] = v.z; p[3] = v.w;
  }
  __syncthreads();

  const int fg = (tid & 7) * 8;
  const int ng = (tid >> 3) * 8;

  float4 a0[8], a1[8];
#pragma unroll
  for (int i = 0; i < 8; ++i) {
    a0[i] = make_float4(0.f, 0.f, 0.f, 0.f);
    a1[i] = make_float4(0.f, 0.f, 0.f, 0.f);
  }

#pragma unroll 4
  for (int d = 0; d < DF; ++d) {
    float4 w0 = *(const float4*)&Ws[d * DF + fg];
    float4 w1 = *(const float4*)&Ws[d * DF + fg + 4];
#pragma unroll
    for (int i = 0; i < 8; ++i) {
      float xv = Xs[(ng + i) * 65 + d];
      a0[i].x += xv * w0.x; a0[i].y += xv * w0.y;
      a0[i].z += xv * w0.z; a0[i].w += xv * w0.w;
      a1[i].x += xv * w1.x; a1[i].y += xv * w1.y;
      a1[i].z += xv * w1.z; a1[i].w += xv * w1.w;
    }
  }

  float4 bb0 = *(const float4*)&bias[fg];
  float4 bb1 = *(const float4*)&bias[fg + 4];

#pragma unroll
  for (int i = 0; i < 8; ++i) {
    int n = ng + i;
    if (n < nrem) {
      float* op = out + (size_t)(n0 + n) * DF + fg;
      float4 o0 = *(float4*)op;
      float4 o1 = *(float4*)(op + 4);
      o0.x += a0[i].x + bb0.x; o0.y += a0[i].y + bb0.y;
      o0.z += a0[i].z + bb0.z; o0.w += a0[i].w + bb0.w;
      o1.x += a1[i].x + bb1.x; o1.y += a1[i].y + bb1.y;
      o1.z += a1[i].z + bb1.z; o1.w += a1[i].w + bb1.w;
      if (mode == 1) {
        o0.x = fmaxf(o0.x, 0.f); o0.y = fmaxf(o0.y, 0.f);
        o0.z = fmaxf(o0.z, 0.f); o0.w = fmaxf(o0.w, 0.f);
        o1.x = fmaxf(o1.x, 0.f); o1.y = fmaxf(o1.y, 0.f);
        o1.z = fmaxf(o1.z, 0.f); o1.w = fmaxf(o1.w, 0.f);
      }
      *(float4*)op = o0;
      *(float4*)(op + 4) = o1;
    }
  }
}

__global__ __launch_bounds__(256) void rgcn_scatter(
    const int* __restrict__ src, const int* __restrict__ dst,
    const int* __restrict__ et,
    const unsigned short* __restrict__ hb,
    float* __restrict__ out,
    int E, int N, int r0, int r1)
{
  long long g = (long long)blockIdx.x * 256 + threadIdx.x;
  int e = (int)(g >> 4);
  if (e >= E) return;
  int r = et[e];
  if (r < r0 || r >= r1) return;
  int f4 = ((int)g & 15) * 4;
  int s = src[e];
  int d = dst[e];
  ushort4 u = *(const ushort4*)&hb[(((size_t)(r - r0) * N + s) << 6) + f4];
  float* o = out + ((size_t)d << 6) + f4;
  atomicAdd(o + 0, bf2f(u.x));
  atomicAdd(o + 1, bf2f(u.y));
  atomicAdd(o + 2, bf2f(u.z));
  atomicAdd(o + 3, bf2f(u.w));
}

// ---------------------------------------------------------------------------
extern "C" void kernel_launch(void* const* d_in, const int* in_sizes, int n_in,
                              void* d_out, int out_size, void* d_ws, size_t ws_size,
                              hipStream_t stream) {
  const int* adj    = (const int*)d_in[0];    // [2, E]
  const float* feat = (const float*)d_in[1];  // [N, 64]
  const int* et     = (const int*)d_in[2];    // [E]
  const float* W1   = (const float*)d_in[3];
  const float* rt1  = (const float*)d_in[4];
  const float* b1   = (const float*)d_in[5];
  const float* W2   = (const float*)d_in[6];
  const float* rt2  = (const float*)d_in[7];
  const float* b2   = (const float*)d_in[8];

  const int E = in_sizes[0] / 2;
  const int N = in_sizes[1] / DF;
  const int* srcp = adj;
  const int* dstp = adj + E;

  float* out = (float*)d_out;
  const size_t ND = (size_t)N * DF;
  const int NB = (N + DPB - 1) >> DPB_SHIFT;
  const int ebk = (E + EPB - 1) / EPB;

  // ws layout: xb bf16[N,64] | xb2 bf16[N,64] | wfrag[18*512 bf16x8] |
  //            binned u32[E] | relof int[ebk*NB] | bcnt[NB] | boff[NB+1]
  const size_t wfrag_elems = (size_t)18 * 512;
  const size_t need = ND * 2 + ND * 2 + wfrag_elems * 16 +
                      (size_t)E * 4 + (size_t)ebk * NB * 4 +
                      ((size_t)2 * NB + 1) * 4;

  if (ws_size >= need && NB <= NBMAX && N < (1 << 17)) {
    unsigned short* xb  = (unsigned short*)d_ws;
    unsigned short* xb2 = xb + ND;
    bf16x8* wfrag = (bf16x8*)(xb2 + ND);
    unsigned int* binned = (unsigned int*)(wfrag + wfrag_elems);
    int* relof = (int*)(binned + E);
    int* bcnt = relof + (size_t)ebk * NB;
    int* boff = bcnt + NB;

    // ---- fused prep: wfrag pack + feat->bf16 + bcnt zero ----
    const int n8 = (int)(ND / 8);
    prep<<<18 + (n8 + 511) / 512, 512, 0, stream>>>(
        W1, rt1, W2, rt2, wfrag, feat, xb, n8, bcnt, NB);

    // ---- build bucket-grouped edge list once (same graph both layers) ----
    bucket_count<<<ebk, 512, 0, stream>>>(dstp, bcnt, relof, E, NB);
    scan_buckets<<<1, 1024, 0, stream>>>(bcnt, boff, NB, E);
    bin_scatter<<<ebk, 512, 0, stream>>>(srcp, dstp, et, boff, relof,
                                         binned, E, NB);

    // ---- layer 1: out = relu( sum_r agg_r@W1_r + feat@rt1 + b1 ) ----
    gather_gemm<<<NB, 512, 0, stream>>>(binned, boff, xb, wfrag, b1,
                                        out, xb2, N, 1);
    // ---- layer 2 ----
    gather_gemm<<<NB, 512, 0, stream>>>(binned, boff, xb2,
                                        wfrag + (size_t)9 * 512, b2,
                                        out, nullptr, N, 0);
    return;
  }

  // ---------------- fallback: atomic scatter ----------------
  const int nblk = (N + 127) / 128;
  size_t per_rel = ND * sizeof(unsigned short);
  size_t xmid_b = ND * sizeof(float);
  int RC = 1;
  if (ws_size > per_rel + xmid_b) {
    size_t rc = (ws_size - xmid_b) / per_rel;
    RC = rc >= NREL ? NREL : (int)rc;
  }
  unsigned short* hb = (unsigned short*)d_ws;
  float* xmid = (float*)((char*)d_ws + (size_t)RC * per_rel);
  const int sblk = (int)(((size_t)E * 16 + 255) / 256);

  for (int layer = 0; layer < 2; ++layer) {
    const float* xin = layer ? xmid : feat;
    const float* W   = layer ? W2 : W1;
    const float* rt  = layer ? rt2 : rt1;
    const float* bs  = layer ? b2 : b1;
    float* o         = layer ? out : xmid;

    hipMemsetAsync(o, 0, ND * sizeof(float), stream);
    for (int r0 = 0; r0 < NREL; r0 += RC) {
      int rc = (NREL - r0) < RC ? (NREL - r0) : RC;
      rgcn_transform<<<dim3(nblk, rc), 128, 0, stream>>>(
          xin, W + (size_t)r0 * DF * DF, hb, N);
      rgcn_scatter<<<sblk, 256, 0, stream>>>(
          srcp, dstp, et, hb, o, E, N, r0, r0 + rc);
    }
    rgcn_root_epilogue<<<nblk, 128, 0, stream>>>(xin, rt, bs, o, N,
                                                 layer == 0 ? 1 : 2);
  }
}

// Round 17
// 147.882 us; speedup vs baseline: 1.0714x; 1.0714x over previous
//
#include <hip/hip_runtime.h>
#include <cstdint>
#include <cstddef>

#define DF 64          // feature dim
#define NREL 8         // relations
#define DPB 64         // dst nodes per coarse bucket
#define DPB_SHIFT 6
#define NBMAX 1024     // max coarse buckets supported by LDS kernels
#define EPB 4096       // edges per binning block. DO NOT SHRINK: per-block
                       // cursor setup is O(NB); EPB=2048 regressed twice (R8,R13)
#define BCAP 3072      // per-bucket record capacity in gather_sum LDS
#define NKEY 512       // (local_dst 6b << 3) | rel 3b

typedef __attribute__((ext_vector_type(8))) short bf16x8;
typedef __attribute__((ext_vector_type(4))) float f32x4;

// ---- bf16 helpers (RNE) ---------------------------------------------------
static __device__ __forceinline__ unsigned short f2bf(float f) {
  unsigned int u = __float_as_uint(f);
  u += 0x7FFFu + ((u >> 16) & 1u);
  return (unsigned short)(u >> 16);
}
static __device__ __forceinline__ float bf2f(unsigned short s) {
  return __uint_as_float((unsigned int)s << 16);
}

// ---------------------------------------------------------------------------
// prep: blocks 0..17 pack weights into bf16 MFMA A-fragments
//       (A[row=f][k] = W[k][f]; mats 0..7=W1, 8=root1, 9..16=W2, 17=root2);
//       blocks 18.. convert feat fp32 -> xb bf16; block 18 zeroes bcnt.
// ---------------------------------------------------------------------------
__global__ __launch_bounds__(512) void prep(
    const float* __restrict__ W1, const float* __restrict__ rt1,
    const float* __restrict__ W2, const float* __restrict__ rt2,
    bf16x8* __restrict__ frag,
    const float* __restrict__ x, unsigned short* __restrict__ xb, int n8,
    int* __restrict__ bcnt, int NB)
{
  const int b = blockIdx.x;
  const int t = threadIdx.x;

  if (b < 18) {
    const float* W = (b < 8)  ? (W1 + (size_t)b * 4096)
                   : (b == 8) ? rt1
                   : (b < 17) ? (W2 + (size_t)(b - 9) * 4096)
                              : rt2;
    const int ft = t >> 7;
    const int ks = (t >> 6) & 1;
    const int l  = t & 63;
    const int col = ft * 16 + (l & 15);
    const int k0  = ks * 32 + (l >> 4) * 8;
    bf16x8 f;
#pragma unroll
    for (int j = 0; j < 8; ++j)
      f[j] = (short)f2bf(W[(size_t)(k0 + j) * 64 + col]);
    frag[(((size_t)b * 4 + ft) * 2 + ks) * 64 + l] = f;
    return;
  }

  if (b == 18) {
    for (int i = t; i < NB; i += 512) bcnt[i] = 0;
  }

  const int i = (b - 18) * 512 + t;
  if (i < n8) {
    const float4 v0 = *(const float4*)&x[(size_t)i * 8];
    const float4 v1 = *(const float4*)&x[(size_t)i * 8 + 4];
    uint4 pk;
    pk.x = (unsigned)f2bf(v0.x) | ((unsigned)f2bf(v0.y) << 16);
    pk.y = (unsigned)f2bf(v0.z) | ((unsigned)f2bf(v0.w) << 16);
    pk.z = (unsigned)f2bf(v1.x) | ((unsigned)f2bf(v1.y) << 16);
    pk.w = (unsigned)f2bf(v1.z) | ((unsigned)f2bf(v1.w) << 16);
    *(uint4*)&xb[(size_t)i * 8] = pk;
  }
}

// ---------------------------------------------------------------------------
// CSR-lite build (one-pass scatter via saved per-block reservations)
// record (u32): rel[3] << 24 | src[17] << 7 | local_dst[6]
// ---------------------------------------------------------------------------
__global__ __launch_bounds__(512) void bucket_count(
    const int* __restrict__ dst, int* __restrict__ bcnt,
    int* __restrict__ relof, int E, int NB)
{
  __shared__ int lh[NBMAX];
  const int t = threadIdx.x;
  for (int i = t; i < NB; i += 512) lh[i] = 0;
  __syncthreads();
  const int base = blockIdx.x * EPB;
  const int cnt = min(EPB, E - base);
  for (int k = t; k < cnt; k += 512)
    atomicAdd(&lh[dst[base + k] >> DPB_SHIFT], 1);
  __syncthreads();
  int* rrow = relof + (size_t)blockIdx.x * NB;
  for (int i = t; i < NB; i += 512) {
    int c = lh[i];
    rrow[i] = c ? atomicAdd(&bcnt[i], c) : 0;
  }
}

__global__ __launch_bounds__(1024) void scan_buckets(
    const int* __restrict__ bcnt, int* __restrict__ boff, int NB, int E)
{
  __shared__ int sc[1024];
  const int t = threadIdx.x;
  int v = (t < NB) ? bcnt[t] : 0;
  sc[t] = v;
  __syncthreads();
  for (int off = 1; off < 1024; off <<= 1) {
    int u = (t >= off) ? sc[t - off] : 0;
    __syncthreads();
    sc[t] += u;
    __syncthreads();
  }
  if (t < NB) boff[t] = sc[t] - v;
  if (t == 0) boff[NB] = E;
}

__global__ __launch_bounds__(512) void bin_scatter(
    const int* __restrict__ src, const int* __restrict__ dst,
    const int* __restrict__ et,
    const int* __restrict__ boff, const int* __restrict__ relof,
    unsigned int* __restrict__ binned, int E, int NB)
{
  __shared__ int cur[NBMAX];
  const int t = threadIdx.x;
  const int* rrow = relof + (size_t)blockIdx.x * NB;
  for (int i = t; i < NB; i += 512) cur[i] = boff[i] + rrow[i];
  __syncthreads();
  const int base = blockIdx.x * EPB;
  const int cnt = min(EPB, E - base);
  for (int k = t; k < cnt; k += 512) {
    int e = base + k;
    int d = dst[e];
    int pos = atomicAdd(&cur[d >> DPB_SHIFT], 1);
    binned[pos] = ((unsigned)et[e] << 24) | ((unsigned)src[e] << 7) |
                  ((unsigned)d & (DPB - 1));
  }
}

// ---------------------------------------------------------------------------
// gather_sum: per 64-dst bucket, LDS-sort records by key=(local_dst<<3)|rel,
// then 64 nodes x 8 lanes accumulate x-rows per relation segment and write
// s[node][rel][64] (bf16). Barrier-free gather stream (32 loads/thread avg)
// is the MLP advantage over fusing the GEMM in (R15/R16 both regressed).
// ---------------------------------------------------------------------------
static __device__ __forceinline__ void gadd(
    float* __restrict__ acc, const uint4& u)
{
  acc[0] += bf2f((unsigned short)u.x);
  acc[1] += bf2f((unsigned short)(u.x >> 16));
  acc[2] += bf2f((unsigned short)u.y);
  acc[3] += bf2f((unsigned short)(u.y >> 16));
  acc[4] += bf2f((unsigned short)u.z);
  acc[5] += bf2f((unsigned short)(u.z >> 16));
  acc[6] += bf2f((unsigned short)u.w);
  acc[7] += bf2f((unsigned short)(u.w >> 16));
}

__global__ __launch_bounds__(512) void gather_sum(
    const unsigned int* __restrict__ binned,
    const int* __restrict__ boff,
    const unsigned short* __restrict__ xb,   // [N][64] bf16
    unsigned short* __restrict__ s,          // [N][8][64] bf16
    int N)
{
  __shared__ unsigned int srt[BCAP];
  __shared__ int h[NKEY], sc[NKEY], cur[NKEY];
  __shared__ int wsum[8];
  const int t = threadIdx.x;
  const int b = blockIdx.x;
  const int beg = boff[b], end = boff[b + 1];
  const int m = min(end - beg, BCAP);

  h[t] = 0;            // t covers 0..511 = NKEY exactly
  __syncthreads();
  for (int k = t; k < m; k += 512) {
    unsigned w = binned[beg + k];
    atomicAdd(&h[((w & (DPB - 1)) << 3) | (w >> 24)], 1);
  }
  __syncthreads();

  // wave-shuffle inclusive scan of h -> sc
  {
    const int lane = t & 63;
    const int wv = t >> 6;
    int v = h[t];
    int incl = v;
#pragma unroll
    for (int off = 1; off < 64; off <<= 1) {
      int u = __shfl_up(incl, off);
      if (lane >= off) incl += u;
    }
    if (lane == 63) wsum[wv] = incl;
    __syncthreads();
    int wo = 0;
    for (int w2 = 0; w2 < wv; ++w2) wo += wsum[w2];
    sc[t] = incl + wo;
    cur[t] = sc[t] - v;
  }
  __syncthreads();

  for (int k = t; k < m; k += 512) {
    unsigned w = binned[beg + k];
    int pos = atomicAdd(&cur[((w & (DPB - 1)) << 3) | (w >> 24)], 1);
    srt[pos] = w;
  }
  __syncthreads();

  const int nl = t >> 3;                    // 0..63 local node
  const int node = (b << DPB_SHIFT) + nl;
  const int l8 = (t & 7) * 8;               // feature offset (8 bf16 = 16B)
  if (node >= N) return;
  const int ovf = end - beg - BCAP;         // >0 only on pathological buckets

#define XADDR(wv) ((const uint4*)&xb[(((size_t)(((wv) >> 7) & 0x1FFFFu)) << 6) + l8])
  for (int r = 0; r < NREL; ++r) {
    const int kk = (nl << 3) | r;
    int p = sc[kk] - h[kk];
    const int pe = sc[kk];
    float acc[8];
#pragma unroll
    for (int i = 0; i < 8; ++i) acc[i] = 0.f;

    for (; p + 3 < pe; p += 4) {
      unsigned w0 = srt[p],     w1 = srt[p + 1];
      unsigned w2 = srt[p + 2], w3 = srt[p + 3];
      uint4 u0 = *XADDR(w0), u1 = *XADDR(w1);
      uint4 u2 = *XADDR(w2), u3 = *XADDR(w3);
      gadd(acc, u0); gadd(acc, u1); gadd(acc, u2); gadd(acc, u3);
    }
    for (; p < pe; ++p) {
      unsigned w0 = srt[p];
      uint4 u0 = *XADDR(w0);
      gadd(acc, u0);
    }
    if (ovf > 0) {   // slow path, ~never taken
      for (int k = 0; k < ovf; ++k) {
        unsigned w0 = binned[beg + BCAP + k];
        if ((int)(w0 & (DPB - 1)) == nl && (int)(w0 >> 24) == r) {
          uint4 u0 = *XADDR(w0);
          gadd(acc, u0);
        }
      }
    }

    uint4 pk;
    pk.x = (unsigned)f2bf(acc[0]) | ((unsigned)f2bf(acc[1]) << 16);
    pk.y = (unsigned)f2bf(acc[2]) | ((unsigned)f2bf(acc[3]) << 16);
    pk.z = (unsigned)f2bf(acc[4]) | ((unsigned)f2bf(acc[5]) << 16);
    pk.w = (unsigned)f2bf(acc[6]) | ((unsigned)f2bf(acc[7]) << 16);
    *(uint4*)&s[(((size_t)node * NREL + r) << 6) + l8] = pk;
  }
#undef XADDR
}

// ---------------------------------------------------------------------------
// gemm_fused: out[n][f] = maybe_relu( sum_r s[n][r]@W_r + x@root + b )
// K-accumulated MFMA over 9 slabs (8 rel sums + root on xb).
// A = W^T fragments (wfrag), B = s/xb rows; C col=node, row=f (wide stores).
// store_out=0 skips the fp32 out write (layer 1's is dead — layer 2
// overwrites it); xbn (bf16 next-layer input) is emitted when non-null.
// ---------------------------------------------------------------------------
__global__ __launch_bounds__(256) void gemm_fused(
    const unsigned short* __restrict__ s,    // [N][8][64] bf16
    const unsigned short* __restrict__ xb,   // [N][64] bf16
    const bf16x8* __restrict__ wfrag,        // [9][4][2][64] layer base
    const float* __restrict__ bias,          // [64]
    float* __restrict__ out,                 // [N][64] fp32
    unsigned short* __restrict__ xbn,        // [N][64] bf16 or null
    int N, int do_relu, int store_out)
{
  const int tid = threadIdx.x;
  const int l  = tid & 63;
  const int w  = tid >> 6;
  const int n0 = blockIdx.x * 128 + w * 32;
  const int lr = l & 15;
  const int lg = l >> 4;

  f32x4 acc[4][2];
#pragma unroll
  for (int mt = 0; mt < 4; ++mt)
#pragma unroll
    for (int nt = 0; nt < 2; ++nt)
      acc[mt][nt] = (f32x4)(0.f);

  const int node0 = n0 + lr;        // nt=0 node
  const int node1 = n0 + 16 + lr;   // nt=1 node

  for (int r = 0; r < 9; ++r) {
    const bf16x8* wf = wfrag + (size_t)r * 512;
    bf16x8 a[4][2];
#pragma unroll
    for (int mt = 0; mt < 4; ++mt)
#pragma unroll
      for (int ks = 0; ks < 2; ++ks)
        a[mt][ks] = wf[(mt * 2 + ks) * 64 + l];

    bf16x8 b[2][2];
#pragma unroll
    for (int nt = 0; nt < 2; ++nt) {
      const int node = nt ? node1 : node0;
#pragma unroll
      for (int ks = 0; ks < 2; ++ks) {
        if (node < N) {
          const unsigned short* bp = (r < 8)
              ? &s[(((size_t)node * NREL + r) << 6) + ks * 32 + lg * 8]
              : &xb[((size_t)node << 6) + ks * 32 + lg * 8];
          b[nt][ks] = *(const bf16x8*)bp;
        } else {
          b[nt][ks] = (bf16x8)(short)0;
        }
      }
    }

#pragma unroll
    for (int ks = 0; ks < 2; ++ks)
#pragma unroll
      for (int mt = 0; mt < 4; ++mt)
#pragma unroll
        for (int nt = 0; nt < 2; ++nt)
          acc[mt][nt] = __builtin_amdgcn_mfma_f32_16x16x32_bf16(
              a[mt][ks], b[nt][ks], acc[mt][nt], 0, 0, 0);
  }

#pragma unroll
  for (int nt = 0; nt < 2; ++nt) {
    const int node = nt ? node1 : node0;
    if (node < N) {
#pragma unroll
      for (int mt = 0; mt < 4; ++mt) {
        const int f0 = mt * 16 + lg * 4;
        float4 bb = *(const float4*)&bias[f0];
        float4 v = make_float4(acc[mt][nt][0] + bb.x,
                               acc[mt][nt][1] + bb.y,
                               acc[mt][nt][2] + bb.z,
                               acc[mt][nt][3] + bb.w);
        if (do_relu) {
          v.x = fmaxf(v.x, 0.f); v.y = fmaxf(v.y, 0.f);
          v.z = fmaxf(v.z, 0.f); v.w = fmaxf(v.w, 0.f);
        }
        if (store_out)
          *(float4*)&out[((size_t)node << 6) + f0] = v;
        if (xbn) {
          uint2 pk;
          pk.x = (unsigned)f2bf(v.x) | ((unsigned)f2bf(v.y) << 16);
          pk.y = (unsigned)f2bf(v.z) | ((unsigned)f2bf(v.w) << 16);
          *(uint2*)&xbn[((size_t)node << 6) + f0] = pk;
        }
      }
    }
  }
}

// ---------------------------------------------------------------------------
// FALLBACK path kernels (ws too small): fp32 vector transform + atomic scatter
// ---------------------------------------------------------------------------
__global__ __launch_bounds__(128) void rgcn_transform(
    const float* __restrict__ x,
    const float* __restrict__ Wc,
    unsigned short* __restrict__ hb,
    int N)
{
  const int r = blockIdx.y;
  const float* W = Wc + (size_t)r * DF * DF;

  __shared__ float Ws[DF * DF];
  __shared__ float Xs[128 * 65];

  const int tid = threadIdx.x;
  const int n0 = blockIdx.x * 128;
  const int nrem = N - n0;

  {
    const float4* Wv = (const float4*)W;
    float4* Wsv = (float4*)Ws;
#pragma unroll
    for (int j = 0; j < 8; ++j) Wsv[tid + j * 128] = Wv[tid + j * 128];
  }
#pragma unroll
  for (int j = 0; j < 16; ++j) {
    int idx = tid + j * 128;
    int n = idx >> 4;
    int c4 = (idx & 15) * 4;
    float4 v = make_float4(0.f, 0.f, 0.f, 0.f);
    if (n < nrem) v = *(const float4*)&x[(size_t)(n0 + n) * DF + c4];
    float* p = &Xs[n * 65 + c4];
    p[0] = v.x; p[1] = v.y; p[2] = v.z; p[3] = v.w;
  }
  __syncthreads();

  const int fg = (tid & 7) * 8;
  const int ng = (tid >> 3) * 8;

  float4 a0[8], a1[8];
#pragma unroll
  for (int i = 0; i < 8; ++i) {
    a0[i] = make_float4(0.f, 0.f, 0.f, 0.f);
    a1[i] = make_float4(0.f, 0.f, 0.f, 0.f);
  }

#pragma unroll 4
  for (int d = 0; d < DF; ++d) {
    float4 w0 = *(const float4*)&Ws[d * DF + fg];
    float4 w1 = *(const float4*)&Ws[d * DF + fg + 4];
#pragma unroll
    for (int i = 0; i < 8; ++i) {
      float xv = Xs[(ng + i) * 65 + d];
      a0[i].x += xv * w0.x; a0[i].y += xv * w0.y;
      a0[i].z += xv * w0.z; a0[i].w += xv * w0.w;
      a1[i].x += xv * w1.x; a1[i].y += xv * w1.y;
      a1[i].z += xv * w1.z; a1[i].w += xv * w1.w;
    }
  }

#pragma unroll
  for (int i = 0; i < 8; ++i) {
    int n = ng + i;
    if (n < nrem) {
      uint4 pk;
      pk.x = (unsigned)f2bf(a0[i].x) | ((unsigned)f2bf(a0[i].y) << 16);
      pk.y = (unsigned)f2bf(a0[i].z) | ((unsigned)f2bf(a0[i].w) << 16);
      pk.z = (unsigned)f2bf(a1[i].x) | ((unsigned)f2bf(a1[i].y) << 16);
      pk.w = (unsigned)f2bf(a1[i].z) | ((unsigned)f2bf(a1[i].w) << 16);
      unsigned short* op = hb + (((size_t)r * N + (n0 + n)) << 6) + fg;
      *(uint4*)op = pk;
    }
  }
}

__global__ __launch_bounds__(128) void rgcn_root_epilogue(
    const float* __restrict__ x,
    const float* __restrict__ root,
    const float* __restrict__ bias,
    float* __restrict__ out,
    int N, int mode)
{
  __shared__ float Ws[DF * DF];
  __shared__ float Xs[128 * 65];

  const int tid = threadIdx.x;
  const int n0 = blockIdx.x * 128;
  const int nrem = N - n0;

  {
    const float4* Wv = (const float4*)root;
    float4* Wsv = (float4*)Ws;
#pragma unroll
    for (int j = 0; j < 8; ++j) Wsv[tid + j * 128] = Wv[tid + j * 128];
  }
#pragma unroll
  for (int j = 0; j < 16; ++j) {
    int idx = tid + j * 128;
    int n = idx >> 4;
    int c4 = (idx & 15) * 4;
    float4 v = make_float4(0.f, 0.f, 0.f, 0.f);
    if (n < nrem) v = *(const float4*)&x[(size_t)(n0 + n) * DF + c4];
    float* p = &Xs[n * 65 + c4];
    p[0] = v.x; p[1] = v.y; p[2] = v.z; p[3] = v.w;
  }
  __syncthreads();

  const int fg = (tid & 7) * 8;
  const int ng = (tid >> 3) * 8;

  float4 a0[8], a1[8];
#pragma unroll
  for (int i = 0; i < 8; ++i) {
    a0[i] = make_float4(0.f, 0.f, 0.f, 0.f);
    a1[i] = make_float4(0.f, 0.f, 0.f, 0.f);
  }

#pragma unroll 4
  for (int d = 0; d < DF; ++d) {
    float4 w0 = *(const float4*)&Ws[d * DF + fg];
    float4 w1 = *(const float4*)&Ws[d * DF + fg + 4];
#pragma unroll
    for (int i = 0; i < 8; ++i) {
      float xv = Xs[(ng + i) * 65 + d];
      a0[i].x += xv * w0.x; a0[i].y += xv * w0.y;
      a0[i].z += xv * w0.z; a0[i].w += xv * w0.w;
      a1[i].x += xv * w1.x; a1[i].y += xv * w1.y;
      a1[i].z += xv * w1.z; a1[i].w += xv * w1.w;
    }
  }

  float4 bb0 = *(const float4*)&bias[fg];
  float4 bb1 = *(const float4*)&bias[fg + 4];

#pragma unroll
  for (int i = 0; i < 8; ++i) {
    int n = ng + i;
    if (n < nrem) {
      float* op = out + (size_t)(n0 + n) * DF + fg;
      float4 o0 = *(float4*)op;
      float4 o1 = *(float4*)(op + 4);
      o0.x += a0[i].x + bb0.x; o0.y += a0[i].y + bb0.y;
      o0.z += a0[i].z + bb0.z; o0.w += a0[i].w + bb0.w;
      o1.x += a1[i].x + bb1.x; o1.y += a1[i].y + bb1.y;
      o1.z += a1[i].z + bb1.z; o1.w += a1[i].w + bb1.w;
      if (mode == 1) {
        o0.x = fmaxf(o0.x, 0.f); o0.y = fmaxf(o0.y, 0.f);
        o0.z = fmaxf(o0.z, 0.f); o0.w = fmaxf(o0.w, 0.f);
        o1.x = fmaxf(o1.x, 0.f); o1.y = fmaxf(o1.y, 0.f);
        o1.z = fmaxf(o1.z, 0.f); o1.w = fmaxf(o1.w, 0.f);
      }
      *(float4*)op = o0;
      *(float4*)(op + 4) = o1;
    }
  }
}

__global__ __launch_bounds__(256) void rgcn_scatter(
    const int* __restrict__ src, const int* __restrict__ dst,
    const int* __restrict__ et,
    const unsigned short* __restrict__ hb,
    float* __restrict__ out,
    int E, int N, int r0, int r1)
{
  long long g = (long long)blockIdx.x * 256 + threadIdx.x;
  int e = (int)(g >> 4);
  if (e >= E) return;
  int r = et[e];
  if (r < r0 || r >= r1) return;
  int f4 = ((int)g & 15) * 4;
  int s = src[e];
  int d = dst[e];
  ushort4 u = *(const ushort4*)&hb[(((size_t)(r - r0) * N + s) << 6) + f4];
  float* o = out + ((size_t)d << 6) + f4;
  atomicAdd(o + 0, bf2f(u.x));
  atomicAdd(o + 1, bf2f(u.y));
  atomicAdd(o + 2, bf2f(u.z));
  atomicAdd(o + 3, bf2f(u.w));
}

// ---------------------------------------------------------------------------
extern "C" void kernel_launch(void* const* d_in, const int* in_sizes, int n_in,
                              void* d_out, int out_size, void* d_ws, size_t ws_size,
                              hipStream_t stream) {
  const int* adj    = (const int*)d_in[0];    // [2, E]
  const float* feat = (const float*)d_in[1];  // [N, 64]
  const int* et     = (const int*)d_in[2];    // [E]
  const float* W1   = (const float*)d_in[3];
  const float* rt1  = (const float*)d_in[4];
  const float* b1   = (const float*)d_in[5];
  const float* W2   = (const float*)d_in[6];
  const float* rt2  = (const float*)d_in[7];
  const float* b2   = (const float*)d_in[8];

  const int E = in_sizes[0] / 2;
  const int N = in_sizes[1] / DF;
  const int* srcp = adj;
  const int* dstp = adj + E;

  float* out = (float*)d_out;
  const size_t ND = (size_t)N * DF;
  const int nblk = (N + 127) / 128;
  const int NB = (N + DPB - 1) >> DPB_SHIFT;
  const int ebk = (E + EPB - 1) / EPB;

  // ws layout: s bf16[N,8,64] | xb bf16[N,64] | xb2 bf16[N,64] |
  //            wfrag[18*512 bf16x8] | binned u32[E] | relof int[ebk*NB] |
  //            bcnt[NB] | boff[NB+1]
  const size_t wfrag_elems = (size_t)18 * 512;
  const size_t need = 8 * ND * 2 + ND * 2 + ND * 2 + wfrag_elems * 16 +
                      (size_t)E * 4 + (size_t)ebk * NB * 4 +
                      ((size_t)2 * NB + 1) * 4;

  if (ws_size >= need && NB <= NBMAX && N < (1 << 17)) {
    unsigned short* s   = (unsigned short*)d_ws;
    unsigned short* xb  = s + 8 * ND;
    unsigned short* xb2 = xb + ND;
    bf16x8* wfrag = (bf16x8*)(xb2 + ND);
    unsigned int* binned = (unsigned int*)(wfrag + wfrag_elems);
    int* relof = (int*)(binned + E);
    int* bcnt = relof + (size_t)ebk * NB;
    int* boff = bcnt + NB;

    // ---- fused prep: wfrag pack + feat->bf16 + bcnt zero ----
    const int n8 = (int)(ND / 8);
    prep<<<18 + (n8 + 511) / 512, 512, 0, stream>>>(
        W1, rt1, W2, rt2, wfrag, feat, xb, n8, bcnt, NB);

    // ---- build bucket-grouped edge list once (same graph both layers) ----
    bucket_count<<<ebk, 512, 0, stream>>>(dstp, bcnt, relof, E, NB);
    scan_buckets<<<1, 1024, 0, stream>>>(bcnt, boff, NB, E);
    bin_scatter<<<ebk, 512, 0, stream>>>(srcp, dstp, et, boff, relof,
                                         binned, E, NB);

    // ---- layer 1: xb2 = bf16(relu( sum_r s_r@W1_r + feat@rt1 + b1 ))
    //      (fp32 out write skipped: layer 2 overwrites it) ----
    gather_sum<<<NB, 512, 0, stream>>>(binned, boff, xb, s, N);
    gemm_fused<<<nblk, 256, 0, stream>>>(s, xb, wfrag, b1, out, xb2, N, 1, 0);

    // ---- layer 2 ----
    gather_sum<<<NB, 512, 0, stream>>>(binned, boff, xb2, s, N);
    gemm_fused<<<nblk, 256, 0, stream>>>(s, xb2, wfrag + (size_t)9 * 512,
                                         b2, out, nullptr, N, 0, 1);
    return;
  }

  // ---------------- fallback: atomic scatter ----------------
  size_t per_rel = ND * sizeof(unsigned short);
  size_t xmid_b = ND * sizeof(float);
  int RC = 1;
  if (ws_size > per_rel + xmid_b) {
    size_t rc = (ws_size - xmid_b) / per_rel;
    RC = rc >= NREL ? NREL : (int)rc;
  }
  unsigned short* hb = (unsigned short*)d_ws;
  float* xmid = (float*)((char*)d_ws + (size_t)RC * per_rel);
  const int sblk = (int)(((size_t)E * 16 + 255) / 256);

  for (int layer = 0; layer < 2; ++layer) {
    const float* xin = layer ? xmid : feat;
    const float* W   = layer ? W2 : W1;
    const float* rt  = layer ? rt2 : rt1;
    const float* bs  = layer ? b2 : b1;
    float* o         = layer ? out : xmid;

    hipMemsetAsync(o, 0, ND * sizeof(float), stream);
    for (int r0 = 0; r0 < NREL; r0 += RC) {
      int rc = (NREL - r0) < RC ? (NREL - r0) : RC;
      rgcn_transform<<<dim3(nblk, rc), 128, 0, stream>>>(
          xin, W + (size_t)r0 * DF * DF, hb, N);
      rgcn_scatter<<<sblk, 256, 0, stream>>>(
          srcp, dstp, et, hb, o, E, N, r0, r0 + rc);
    }
    rgcn_root_epilogue<<<nblk, 128, 0, stream>>>(xin, rt, bs, o, N,
                                                 layer == 0 ? 1 : 2);
  }
}